// Round 7
// baseline (209.091 us; speedup 1.0000x reference)
//
#include <hip/hip_runtime.h>
#include <hip/hip_bf16.h>

#define S_ 2048
#define DH_ 64
#define NE_ 8388608  // 8192*1024 elems per activation tensor

using f32x4  = __attribute__((ext_vector_type(4))) float;
using bf16x8 = __attribute__((ext_vector_type(8))) __bf16;
using bf16x4 = __attribute__((ext_vector_type(4))) __bf16;

__device__ __forceinline__ unsigned int f2bf(float f) {
    union { float f; unsigned int u; } x; x.f = f;
    return (x.u + 0x7FFFu + ((x.u >> 16) & 1u)) >> 16;  // RNE
}

// async global->LDS, 16B per lane. LDS dest = wave-uniform base + lane*16.
__device__ __forceinline__ void gl_lds16(const unsigned short* g, unsigned short* l) {
    __builtin_amdgcn_global_load_lds(
        (const __attribute__((address_space(1))) unsigned int*)(const void*)g,
        (__attribute__((address_space(3))) unsigned int*)(void*)l,
        16, 0, 0);
}

// ---------------- weight cvt: 4 x [1024,1024] fp32 -> bf16, concat ----------------
__global__ __launch_bounds__(256) void cvt_w4(const float* __restrict__ w0, const float* __restrict__ w1,
                                              const float* __restrict__ w2, const float* __restrict__ w3,
                                              unsigned short* __restrict__ out) {
    const float* src = blockIdx.y == 0 ? w0 : blockIdx.y == 1 ? w1 : blockIdx.y == 2 ? w2 : w3;
    unsigned short* dst = out + (size_t)blockIdx.y * 1048576;
    int i = (blockIdx.x * 256 + threadIdx.x) * 4;
    float4 v = *(const float4*)&src[i];
    ushort4 h;
    h.x = f2bf(v.x); h.y = f2bf(v.y); h.z = f2bf(v.z); h.w = f2bf(v.w);
    *(ushort4*)&dst[i] = h;
}

// ---------------- fused QKV projection, fp32 A, dbuf pipeline ----------------
// grid (64, 24). range = blockIdx.y>>3 picks A tensor (q/k/v fp32) and weight
// rows [range*1024, +1024) of Wcat. A is reg-staged fp32 -> cvt_pk -> LDS;
// W is global_load_lds. Double-buffered: stage t+1 issued before compute t,
// ONE __syncthreads per K-iter. Q scaled by log2e/32; V written [B,H,DH,S].
__global__ __launch_bounds__(256) void gemm_qkv_f(const float* __restrict__ qf32,
                                                  const float* __restrict__ kf32,
                                                  const float* __restrict__ vf32,
                                                  const unsigned short* __restrict__ Wcat,
                                                  const float* __restrict__ bq,
                                                  const float* __restrict__ bk,
                                                  const float* __restrict__ bvv,
                                                  unsigned short* __restrict__ Qp,
                                                  unsigned short* __restrict__ Kp,
                                                  unsigned short* __restrict__ VTp,
                                                  float scq)
{
    constexpr int K = 1024, BK = 32, NT = K / BK;
    __shared__ unsigned short As[2][128 * BK];
    __shared__ unsigned short Bs[2][128 * BK];

    const int tid = threadIdx.x, lane = tid & 63, wid = tid >> 6;
    const int row0 = blockIdx.x * 128, col0 = blockIdx.y * 128;
    const int range = blockIdx.y >> 3;
    const float* A = range == 0 ? qf32 : range == 1 ? kf32 : vf32;
    const int wm = (wid >> 1) * 64, wn = (wid & 1) * 64;
    const int fr = lane & 15, fg = lane >> 4;

    f32x4 acc[4][4] = {};

    // W staging map (gl_lds, linear)
    const int srow = wid * 16 + (lane >> 2);
    const int scol = (lane & 3) * 8;
    const size_t bbase = (size_t)(col0 + srow) * K + scol;

    // A staging map (regs): thread owns row tid>>1, 16 cols at (tid&1)*16
    const int arow = tid >> 1;
    const int acol = (tid & 1) * 16;
    const float* agp = A + (size_t)(row0 + arow) * K + acol;

    float4 ar[4];
    #pragma unroll
    for (int u = 0; u < 4; ++u) ar[u] = *(const float4*)&agp[4 * u];

    gl_lds16(&Wcat[bbase], &Bs[0][srow * BK + scol]);
    gl_lds16(&Wcat[bbase + (size_t)64 * K], &Bs[0][(srow + 64) * BK + scol]);

    {   // convert + write A tile 0
        bf16x8 h0, h1;
        h0[0] = (__bf16)ar[0].x; h0[1] = (__bf16)ar[0].y; h0[2] = (__bf16)ar[0].z; h0[3] = (__bf16)ar[0].w;
        h0[4] = (__bf16)ar[1].x; h0[5] = (__bf16)ar[1].y; h0[6] = (__bf16)ar[1].z; h0[7] = (__bf16)ar[1].w;
        h1[0] = (__bf16)ar[2].x; h1[1] = (__bf16)ar[2].y; h1[2] = (__bf16)ar[2].z; h1[3] = (__bf16)ar[2].w;
        h1[4] = (__bf16)ar[3].x; h1[5] = (__bf16)ar[3].y; h1[6] = (__bf16)ar[3].z; h1[7] = (__bf16)ar[3].w;
        *(bf16x8*)&As[0][arow * BK + acol] = h0;
        *(bf16x8*)&As[0][arow * BK + acol + 8] = h1;
    }
    __syncthreads();

    for (int t = 0; t < NT; ++t) {
        const int cur = t & 1;
        const bool more = (t + 1 < NT);
        if (more) {
            const int k1 = (t + 1) * BK;
            #pragma unroll
            for (int u = 0; u < 4; ++u) ar[u] = *(const float4*)&agp[k1 + 4 * u];
            gl_lds16(&Wcat[bbase + k1], &Bs[cur ^ 1][srow * BK + scol]);
            gl_lds16(&Wcat[bbase + (size_t)64 * K + k1], &Bs[cur ^ 1][(srow + 64) * BK + scol]);
        }

        bf16x8 af[4], bfr[4];
        #pragma unroll
        for (int i = 0; i < 4; ++i) af[i] = *(const bf16x8*)&As[cur][(wm + i * 16 + fr) * BK + fg * 8];
        #pragma unroll
        for (int i = 0; i < 4; ++i) bfr[i] = *(const bf16x8*)&Bs[cur][(wn + i * 16 + fr) * BK + fg * 8];
        #pragma unroll
        for (int i = 0; i < 4; ++i)
            #pragma unroll
            for (int j = 0; j < 4; ++j)
                acc[i][j] = __builtin_amdgcn_mfma_f32_16x16x32_bf16(af[i], bfr[j], acc[i][j], 0, 0, 0);

        if (more) {
            bf16x8 h0, h1;
            h0[0] = (__bf16)ar[0].x; h0[1] = (__bf16)ar[0].y; h0[2] = (__bf16)ar[0].z; h0[3] = (__bf16)ar[0].w;
            h0[4] = (__bf16)ar[1].x; h0[5] = (__bf16)ar[1].y; h0[6] = (__bf16)ar[1].z; h0[7] = (__bf16)ar[1].w;
            h1[0] = (__bf16)ar[2].x; h1[1] = (__bf16)ar[2].y; h1[2] = (__bf16)ar[2].z; h1[3] = (__bf16)ar[2].w;
            h1[4] = (__bf16)ar[3].x; h1[5] = (__bf16)ar[3].y; h1[6] = (__bf16)ar[3].z; h1[7] = (__bf16)ar[3].w;
            *(bf16x8*)&As[cur ^ 1][arow * BK + acol] = h0;
            *(bf16x8*)&As[cur ^ 1][arow * BK + acol + 8] = h1;
        }
        __syncthreads();
    }

    const float os = range == 0 ? scq : 1.0f;
    const float* bp = range == 0 ? bq : range == 1 ? bk : bvv;
    unsigned short* OP = range == 0 ? Qp : Kp;

    #pragma unroll
    for (int i = 0; i < 4; ++i) {
        #pragma unroll
        for (int j = 0; j < 4; ++j) {
            int colr = (col0 + wn + j * 16 + fr) & 1023;
            float bias = bp[colr];
            int h = colr >> 6, dh = colr & 63;
            if (range == 2) {
                int row = row0 + wm + i * 16 + fg * 4;
                int b = row >> 11, s = row & 2047;
                unsigned int w0 = f2bf(acc[i][j][0] + bias) | (f2bf(acc[i][j][1] + bias) << 16);
                unsigned int w1 = f2bf(acc[i][j][2] + bias) | (f2bf(acc[i][j][3] + bias) << 16);
                *(uint2*)&VTp[((size_t)((b << 4) + h) * 64 + dh) * 2048 + s] = make_uint2(w0, w1);
            } else {
                #pragma unroll
                for (int r = 0; r < 4; ++r) {
                    int row = row0 + wm + i * 16 + fg * 4 + r;
                    int b = row >> 11, s = row & 2047;
                    OP[((((b << 4) + h) * 2048 + s) << 6) + dh] =
                        (unsigned short)f2bf((acc[i][j][r] + bias) * os);
                }
            }
        }
    }
}

// ---------------- output projection: fp32 out = Ctx @ Wo^T + bo (dbuf) ----------------
__global__ __launch_bounds__(256) void gemm_o(const unsigned short* __restrict__ A,
                                              const unsigned short* __restrict__ Bw,
                                              const float* __restrict__ bias,
                                              float* __restrict__ Cf)
{
    constexpr int K = 1024, BK = 32, N = 1024, NT = K / BK;
    __shared__ unsigned short As[2][128 * BK];
    __shared__ unsigned short Bs[2][128 * BK];

    const int tid = threadIdx.x, lane = tid & 63, wid = tid >> 6;
    const int row0 = blockIdx.x * 128, col0 = blockIdx.y * 128;
    const int wm = (wid >> 1) * 64, wn = (wid & 1) * 64;
    const int fr = lane & 15, fg = lane >> 4;

    f32x4 acc[4][4] = {};

    const int srow = wid * 16 + (lane >> 2);
    const int scol = (lane & 3) * 8;
    const size_t abase = (size_t)(row0 + srow) * K + scol;
    const size_t bbase = (size_t)(col0 + srow) * K + scol;

    gl_lds16(&A[abase], &As[0][srow * BK + scol]);
    gl_lds16(&A[abase + (size_t)64 * K], &As[0][(srow + 64) * BK + scol]);
    gl_lds16(&Bw[bbase], &Bs[0][srow * BK + scol]);
    gl_lds16(&Bw[bbase + (size_t)64 * K], &Bs[0][(srow + 64) * BK + scol]);
    __syncthreads();

    for (int t = 0; t < NT; ++t) {
        const int cur = t & 1;
        if (t + 1 < NT) {
            const int k1 = (t + 1) * BK;
            gl_lds16(&A[abase + k1], &As[cur ^ 1][srow * BK + scol]);
            gl_lds16(&A[abase + (size_t)64 * K + k1], &As[cur ^ 1][(srow + 64) * BK + scol]);
            gl_lds16(&Bw[bbase + k1], &Bs[cur ^ 1][srow * BK + scol]);
            gl_lds16(&Bw[bbase + (size_t)64 * K + k1], &Bs[cur ^ 1][(srow + 64) * BK + scol]);
        }

        bf16x8 af[4], bfr[4];
        #pragma unroll
        for (int i = 0; i < 4; ++i) af[i] = *(const bf16x8*)&As[cur][(wm + i * 16 + fr) * BK + fg * 8];
        #pragma unroll
        for (int i = 0; i < 4; ++i) bfr[i] = *(const bf16x8*)&Bs[cur][(wn + i * 16 + fr) * BK + fg * 8];
        #pragma unroll
        for (int i = 0; i < 4; ++i)
            #pragma unroll
            for (int j = 0; j < 4; ++j)
                acc[i][j] = __builtin_amdgcn_mfma_f32_16x16x32_bf16(af[i], bfr[j], acc[i][j], 0, 0, 0);
        __syncthreads();
    }

    #pragma unroll
    for (int i = 0; i < 4; ++i) {
        #pragma unroll
        for (int j = 0; j < 4; ++j) {
            int col = col0 + wn + j * 16 + fr;
            float bv = bias[col];
            #pragma unroll
            for (int r = 0; r < 4; ++r) {
                int row = row0 + wm + i * 16 + fg * 4 + r;
                Cf[(size_t)row * N + col] = acc[i][j][r] + bv;
            }
        }
    }
}

// ---------------- Flash attention v5 (unchanged from r5) ----------------
__global__ __launch_bounds__(512, 4) void attn_fwd5(const unsigned short* __restrict__ Qp,
                                                    const unsigned short* __restrict__ Kp,
                                                    const unsigned short* __restrict__ VTg,
                                                    unsigned short* __restrict__ ctx)
{
    __shared__ unsigned short Ks[64][68];
    __shared__ unsigned short Vt[64][68];
    __shared__ unsigned short Ps[8][16][68];

    const int lin = blockIdx.x;
    const int xcd = lin & 7;
    const int w = lin >> 3;
    const int bh = xcd * 8 + (w & 7);     // XCD owns 8 complete heads
    const int j = 15 - (w >> 3);          // heavy blocks first
    const int b = bh >> 4, h = bh & 15;
    const int tid = threadIdx.x, lane = tid & 63, wid = tid >> 6;
    const int fr = lane & 15, fg = lane >> 4;

    const unsigned short* Qh  = Qp  + (size_t)bh * (S_ * DH_);
    const unsigned short* Kh  = Kp  + (size_t)bh * (S_ * DH_);
    const unsigned short* VTh = VTg + (size_t)bh * (DH_ * S_);

    const int srow = tid >> 3;
    const int scol = (tid & 7) * 8;

    bf16x8 ones;
    #pragma unroll
    for (int i = 0; i < 8; ++i) ones[i] = (__bf16)1.0f;

    const int q0 = j * 128;
    const int ntiles = 2 * (j + 1);
    const int rbase = q0 + wid * 16;
    const int qg = rbase + fr;

    bf16x8 qf[2];
    #pragma unroll
    for (int ks = 0; ks < 2; ++ks)
        qf[ks] = *(const bf16x8*)&Qh[(size_t)qg * 64 + ks * 32 + 8 * fg];

    f32x4 oacc[4] = {};
    float m_run = -3.0e38f, l_run = 0.0f;

    int4 kreg = *(const int4*)&Kh[(size_t)srow * 64 + scol];
    int4 vreg = *(const int4*)&VTh[(size_t)srow * 2048 + scol];

    for (int kt = 0; kt < ntiles; ++kt) {
        const int kv0 = kt * 64;
        __syncthreads();
        *(int4*)&Ks[srow][scol] = kreg;
        *(int4*)&Vt[srow][scol] = vreg;
        if (kt + 1 < ntiles) {
            const int kv1 = kv0 + 64;
            kreg = *(const int4*)&Kh[(size_t)(kv1 + srow) * 64 + scol];
            vreg = *(const int4*)&VTh[(size_t)srow * 2048 + kv1 + scol];
        }
        __syncthreads();

        if (kv0 > rbase + 15) continue;

        f32x4 sacc[4] = {};
        #pragma unroll
        for (int nt = 0; nt < 4; ++nt)
            #pragma unroll
            for (int ks = 0; ks < 2; ++ks) {
                bf16x8 kf = *(const bf16x8*)&Ks[nt * 16 + fr][ks * 32 + 8 * fg];
                sacc[nt] = __builtin_amdgcn_mfma_f32_16x16x32_bf16(kf, qf[ks], sacc[nt], 0, 0, 0);
            }

        if (kv0 + 63 > rbase) {
            const int kbase = kv0 + fg * 4;
            #pragma unroll
            for (int nt = 0; nt < 4; ++nt)
                #pragma unroll
                for (int r = 0; r < 4; ++r)
                    if (kbase + nt * 16 + r > qg) sacc[nt][r] = -3.0e38f;
        }

        float vm = sacc[0][0];
        #pragma unroll
        for (int nt = 0; nt < 4; ++nt)
            #pragma unroll
            for (int r = 0; r < 4; ++r) vm = fmaxf(vm, sacc[nt][r]);
        vm = fmaxf(vm, __shfl_xor(vm, 16));
        vm = fmaxf(vm, __shfl_xor(vm, 32));

        if (!__all(vm - m_run <= 8.0f)) {
            const float mn = fmaxf(m_run, vm);
            const float alpha = exp2f(m_run - mn);
            m_run = mn;
            l_run *= alpha;
            #pragma unroll
            for (int dt = 0; dt < 4; ++dt)
                #pragma unroll
                for (int r = 0; r < 4; ++r) oacc[dt][r] *= alpha;
        }

        #pragma unroll
        for (int nt = 0; nt < 4; ++nt) {
            bf16x4 t;
            t[0] = (__bf16)exp2f(sacc[nt][0] - m_run);
            t[1] = (__bf16)exp2f(sacc[nt][1] - m_run);
            t[2] = (__bf16)exp2f(sacc[nt][2] - m_run);
            t[3] = (__bf16)exp2f(sacc[nt][3] - m_run);
            *(bf16x4*)&Ps[wid][fr][nt * 16 + fg * 4] = t;
        }
        asm volatile("s_waitcnt lgkmcnt(0)" ::: "memory");

        bf16x8 pb[2];
        #pragma unroll
        for (int ks = 0; ks < 2; ++ks)
            pb[ks] = *(const bf16x8*)&Ps[wid][fr][ks * 32 + 8 * fg];

        f32x4 racc = {};
        #pragma unroll
        for (int ks = 0; ks < 2; ++ks)
            racc = __builtin_amdgcn_mfma_f32_16x16x32_bf16(ones, pb[ks], racc, 0, 0, 0);
        #pragma unroll
        for (int dt = 0; dt < 4; ++dt)
            #pragma unroll
            for (int ks = 0; ks < 2; ++ks) {
                bf16x8 vf = *(const bf16x8*)&Vt[dt * 16 + fr][ks * 32 + 8 * fg];
                oacc[dt] = __builtin_amdgcn_mfma_f32_16x16x32_bf16(vf, pb[ks], oacc[dt], 0, 0, 0);
            }
        l_run += racc[0];
    }

    const float linv = 1.0f / l_run;
    unsigned short* cb = &ctx[(size_t)(b * 2048 + qg) * 1024 + h * 64];
    #pragma unroll
    for (int dt = 0; dt < 4; ++dt) {
        unsigned int w0 = f2bf(oacc[dt][0] * linv) | (f2bf(oacc[dt][1] * linv) << 16);
        unsigned int w1 = f2bf(oacc[dt][2] * linv) | (f2bf(oacc[dt][3] * linv) << 16);
        *(uint2*)&cb[dt * 16 + fg * 4] = make_uint2(w0, w1);
    }
}

extern "C" void kernel_launch(void* const* d_in, const int* in_sizes, int n_in,
                              void* d_out, int out_size, void* d_ws, size_t ws_size,
                              hipStream_t stream)
{
    const float* q  = (const float*)d_in[0];
    const float* k  = (const float*)d_in[1];
    const float* v  = (const float*)d_in[2];
    const float* Wq = (const float*)d_in[4];
    const float* bq = (const float*)d_in[5];
    const float* Wk = (const float*)d_in[6];
    const float* bk = (const float*)d_in[7];
    const float* Wv = (const float*)d_in[8];
    const float* bv = (const float*)d_in[9];
    const float* Wo = (const float*)d_in[10];
    const float* bo = (const float*)d_in[11];
    float* out = (float*)d_out;

    unsigned short* Wcat = (unsigned short*)d_ws;          // [Wq;Wk;Wv;Wo] bf16
    unsigned short* Qp   = Wcat + 4 * 1048576;
    unsigned short* Kp   = Qp + NE_;
    unsigned short* VTp  = Kp + NE_;                       // V in [B,H,DH,S]
    unsigned short* Ctx  = VTp + NE_;

    const float SCQ = 0.045084220027780106f;  // log2(e)/sqrt(D)

    dim3 blk(256);
    cvt_w4<<<dim3(1024, 4), blk, 0, stream>>>(Wq, Wk, Wv, Wo, Wcat);

    gemm_qkv_f<<<dim3(64, 24), blk, 0, stream>>>(q, k, v, Wcat, bq, bk, bv, Qp, Kp, VTp, SCQ);

    attn_fwd5<<<dim3(1024), dim3(512), 0, stream>>>(Qp, Kp, VTp, Ctx);

    gemm_o<<<dim3(64, 8), blk, 0, stream>>>(Ctx, Wcat + 3 * 1048576, bo, out);
}

// Round 8
// 205.430 us; speedup vs baseline: 1.0178x; 1.0178x over previous
//
#include <hip/hip_runtime.h>
#include <hip/hip_bf16.h>

#define S_ 2048
#define DH_ 64
#define NE_ 8388608  // 8192*1024 elems per activation tensor

using f32x4  = __attribute__((ext_vector_type(4))) float;
using bf16x8 = __attribute__((ext_vector_type(8))) __bf16;
using bf16x4 = __attribute__((ext_vector_type(4))) __bf16;

__device__ __forceinline__ unsigned int f2bf(float f) {
    union { float f; unsigned int u; } x; x.f = f;
    return (x.u + 0x7FFFu + ((x.u >> 16) & 1u)) >> 16;  // RNE
}

// async global->LDS, 16B per lane. LDS dest = wave-uniform base + lane*16.
__device__ __forceinline__ void gl_lds16(const unsigned short* g, unsigned short* l) {
    __builtin_amdgcn_global_load_lds(
        (const __attribute__((address_space(1))) unsigned int*)(const void*)g,
        (__attribute__((address_space(3))) unsigned int*)(void*)l,
        16, 0, 0);
}

// ---------------- weight cvt: 4 x [1024,1024] fp32 -> bf16, concat ----------------
__global__ __launch_bounds__(256) void cvt_w4(const float* __restrict__ w0, const float* __restrict__ w1,
                                              const float* __restrict__ w2, const float* __restrict__ w3,
                                              unsigned short* __restrict__ out) {
    const float* src = blockIdx.y == 0 ? w0 : blockIdx.y == 1 ? w1 : blockIdx.y == 2 ? w2 : w3;
    unsigned short* dst = out + (size_t)blockIdx.y * 1048576;
    int i = (blockIdx.x * 256 + threadIdx.x) * 4;
    float4 v = *(const float4*)&src[i];
    ushort4 h;
    h.x = f2bf(v.x); h.y = f2bf(v.y); h.z = f2bf(v.z); h.w = f2bf(v.w);
    *(ushort4*)&dst[i] = h;
}

// ---------------- activation cvt: q,k,v fp32 -> bf16, concat ----------------
__global__ __launch_bounds__(256) void cvt_a3(const float* __restrict__ a0, const float* __restrict__ a1,
                                              const float* __restrict__ a2, unsigned short* __restrict__ out) {
    const float* src = blockIdx.y == 0 ? a0 : blockIdx.y == 1 ? a1 : a2;
    unsigned short* dst = out + (size_t)blockIdx.y * NE_;
    int i = (blockIdx.x * 256 + threadIdx.x) * 4;
    float4 v = *(const float4*)&src[i];
    ushort4 h;
    h.x = f2bf(v.x); h.y = f2bf(v.y); h.z = f2bf(v.z); h.w = f2bf(v.w);
    *(ushort4*)&dst[i] = h;
}

// ---------------- fused QKV projection: 256^2 tile, 8-phase pipelined ----------------
// A = actb (bf16, range-selected), B = Wcat rows [0,3072). C scattered per range.
// 8 waves (2M x 4N), BK=64, LDS 128KB = 2buf x {A,B} x 2half x [128][64] bf16.
// st_16x32 swizzle (col^32 when row&4) applied via pre-swizzled global source
// (linear gl_lds dest) + swizzled ds_read. Counted vmcnt(4) at phases 4/8 only.
__global__ __launch_bounds__(512, 2) void gemm_qkv8(const unsigned short* __restrict__ actb,
                                                    const unsigned short* __restrict__ Wcat,
                                                    const float* __restrict__ bq,
                                                    const float* __restrict__ bk,
                                                    const float* __restrict__ bvv,
                                                    unsigned short* __restrict__ Qp,
                                                    unsigned short* __restrict__ Kp,
                                                    unsigned short* __restrict__ VTp,
                                                    float scq)
{
    __shared__ unsigned short lds[65536];   // elems: A [0,32768), B [32768,65536)
    unsigned short* ldsA = lds;
    unsigned short* ldsB = lds + 32768;

    // bijective XCD swizzle: nwg=384, q=48, r=0
    const int orig = blockIdx.x;
    const int lid = (orig & 7) * 48 + (orig >> 3);
    const int bx = lid & 31;        // 32 row tiles
    const int by = lid >> 5;        // 12 col tiles
    const int range = by >> 2;      // 0:Q 1:K 2:V
    const unsigned short* Aact = actb + (size_t)range * NE_;

    const int tid = threadIdx.x, lane = tid & 63, wid = tid >> 6;
    const int fr = lane & 15, fg = lane >> 4;
    const int wid_m = wid >> 2, wid_n = wid & 3;

    // staging maps (per-lane): lds linear dest, pre-swizzled global source
    const int srcRow0 = wid * 16 + (lane >> 3);                 // u=0 row; u=1: +8
    const int scolS = ((((lane & 7) * 16) ^ (lane & 32)) >> 1); // swizzled src col (elems)

    auto STG = [&](int ldsRegion, const unsigned short* g, int grow, int kk) {
        const unsigned short* s0 = g + (size_t)(grow + srcRow0) * 1024 + kk + scolS;
        gl_lds16(s0, lds + ldsRegion + wid * 1024 + lane * 8);
        gl_lds16(s0 + 8 * 1024, lds + ldsRegion + wid * 1024 + 512 + lane * 8);
    };

    // ds_read bases (swizzled): col = ks*32 + (fg*8 ^ flipR)
    const int flipR = (fr & 4) ? 16 : 0;
    const int vA = wid_m * 8192 + fr * 64 + ((fg * 8) ^ flipR);
    const int vB = (wid_n & 1) * 4096 + fr * 64 + ((fg * 8) ^ flipR) + (wid_n >> 1) * 8192;

    f32x4 acc[8][4] = {};
    bf16x8 bfr[4][2];

    // prologue: A-buf0<-T0 (h0,h1), B-buf0<-T0, B-buf1<-T1; retire first 8, keep 4
    STG(0,          Aact, bx * 256,       0);
    STG(8192,       Aact, bx * 256 + 128, 0);
    STG(32768,      Wcat, by * 256,       0);
    STG(32768+8192, Wcat, by * 256 + 128, 0);
    STG(32768+16384,       Wcat, by * 256,       64);
    STG(32768+16384+8192,  Wcat, by * 256 + 128,  64);
    asm volatile("s_waitcnt vmcnt(4)" ::: "memory");
    __builtin_amdgcn_s_barrier();

#define KTILE(BUF, ABUF, TA, BBUF, TB)                                              \
  {                                                                                 \
    _Pragma("unroll")                                                               \
    for (int q = 0; q < 4; ++q) {                                                   \
      if (q == 0) {                                                                 \
        _Pragma("unroll")                                                           \
        for (int j = 0; j < 4; ++j) {                                               \
          bfr[j][0] = *(const bf16x8*)&ldsB[(BUF)*16384 + vB + j*1024];             \
          bfr[j][1] = *(const bf16x8*)&ldsB[(BUF)*16384 + vB + j*1024 + 32];        \
        }                                                                           \
      }                                                                             \
      bf16x8 af[2][2];                                                              \
      _Pragma("unroll")                                                             \
      for (int i2 = 0; i2 < 2; ++i2) {                                              \
        af[i2][0] = *(const bf16x8*)&ldsA[(BUF)*16384 + vA + (q*2+i2)*1024];        \
        af[i2][1] = *(const bf16x8*)&ldsA[(BUF)*16384 + vA + (q*2+i2)*1024 + 32];   \
      }                                                                             \
      if (q == 0) STG((ABUF)*16384,        Aact, bx*256,       ((TA)&15)*64);       \
      if (q == 1) STG((ABUF)*16384 + 8192, Aact, bx*256 + 128, ((TA)&15)*64);       \
      if (q == 2) STG(32768 + (BBUF)*16384,        Wcat, by*256,       ((TB)&15)*64); \
      if (q == 3) { STG(32768 + (BBUF)*16384 + 8192, Wcat, by*256 + 128, ((TB)&15)*64); \
                    asm volatile("s_waitcnt vmcnt(4)" ::: "memory"); }              \
      __builtin_amdgcn_s_barrier();                                                 \
      asm volatile("s_waitcnt lgkmcnt(0)" ::: "memory");                            \
      __builtin_amdgcn_s_setprio(1);                                                \
      _Pragma("unroll")                                                             \
      for (int i2 = 0; i2 < 2; ++i2)                                                \
        _Pragma("unroll")                                                           \
        for (int j = 0; j < 4; ++j) {                                               \
          acc[q*2+i2][j] = __builtin_amdgcn_mfma_f32_16x16x32_bf16(af[i2][0], bfr[j][0], acc[q*2+i2][j], 0, 0, 0); \
          acc[q*2+i2][j] = __builtin_amdgcn_mfma_f32_16x16x32_bf16(af[i2][1], bfr[j][1], acc[q*2+i2][j], 0, 0, 0); \
        }                                                                           \
      __builtin_amdgcn_s_setprio(0);                                                \
      __builtin_amdgcn_s_barrier();                                                 \
    }                                                                               \
  }

    for (int it = 0; it < 8; ++it) {
        const int t0 = 2 * it;
        KTILE(0, 1, t0 + 1, 0, t0 + 2);   // phases 1-4: read buf0; stage A-buf1<-T1, B-buf0<-T2
        KTILE(1, 0, t0 + 2, 1, t0 + 3);   // phases 5-8: read buf1; stage A-buf0<-T2, B-buf1<-T3
    }
#undef KTILE

    asm volatile("s_waitcnt vmcnt(0)" ::: "memory");  // drain dummy prefetches before exit

    // epilogue: wave owns rows [wid_m*128,+128) x cols [wid_n*64,+64) of the 256^2 tile
    const float* bp = range == 0 ? bq : range == 1 ? bk : bvv;
    const float os = range == 0 ? scq : 1.0f;
    unsigned short* OP = range == 0 ? Qp : Kp;
    const int row00 = bx * 256 + wid_m * 128;
    const int col0r = (by & 3) * 256 + wid_n * 64;   // within range [0,1024)

    #pragma unroll
    for (int i = 0; i < 8; ++i) {
        #pragma unroll
        for (int j = 0; j < 4; ++j) {
            int colr = col0r + j * 16 + fr;
            float bias = bp[colr];
            int h = colr >> 6, dh = colr & 63;
            if (range == 2) {
                int row = row00 + i * 16 + fg * 4;
                int b = row >> 11, s = row & 2047;
                unsigned int w0 = f2bf(acc[i][j][0] + bias) | (f2bf(acc[i][j][1] + bias) << 16);
                unsigned int w1 = f2bf(acc[i][j][2] + bias) | (f2bf(acc[i][j][3] + bias) << 16);
                *(uint2*)&VTp[((size_t)((b << 4) + h) * 64 + dh) * 2048 + s] = make_uint2(w0, w1);
            } else {
                #pragma unroll
                for (int r = 0; r < 4; ++r) {
                    int row = row00 + i * 16 + fg * 4 + r;
                    int b = row >> 11, s = row & 2047;
                    OP[((((b << 4) + h) * 2048 + s) << 6) + dh] =
                        (unsigned short)f2bf((acc[i][j][r] + bias) * os);
                }
            }
        }
    }
}

// ---------------- output projection: fp32 out = Ctx @ Wo^T + bo (r5 known-good) ----------------
__global__ __launch_bounds__(256) void gemm_o(const unsigned short* __restrict__ A,
                                              const unsigned short* __restrict__ Bw,
                                              const float* __restrict__ bias,
                                              float* __restrict__ Cf)
{
    constexpr int K = 1024, BK = 32, N = 1024;
    __shared__ unsigned short As[128 * BK];
    __shared__ unsigned short Bs[128 * BK];

    const int tid = threadIdx.x, lane = tid & 63, wid = tid >> 6;
    const int row0 = blockIdx.x * 128, col0 = blockIdx.y * 128;
    const int wm = (wid >> 1) * 64, wn = (wid & 1) * 64;
    const int fr = lane & 15, fg = lane >> 4;

    f32x4 acc[4][4] = {};

    const int srow = wid * 16 + (lane >> 2);
    const int scol = (lane & 3) * 8;
    const size_t abase = (size_t)(row0 + srow) * K + scol;
    const size_t bbase = (size_t)(col0 + srow) * K + scol;
    unsigned short* lA0 = &As[srow * BK + scol];
    unsigned short* lA1 = &As[(srow + 64) * BK + scol];
    unsigned short* lB0 = &Bs[srow * BK + scol];
    unsigned short* lB1 = &Bs[(srow + 64) * BK + scol];

    for (int k0 = 0; k0 < K; k0 += BK) {
        gl_lds16(&A[abase + k0], lA0);
        gl_lds16(&A[abase + (size_t)64 * K + k0], lA1);
        gl_lds16(&Bw[bbase + k0], lB0);
        gl_lds16(&Bw[bbase + (size_t)64 * K + k0], lB1);
        __syncthreads();

        bf16x8 af[4], bfr[4];
        #pragma unroll
        for (int i = 0; i < 4; ++i) af[i] = *(const bf16x8*)&As[(wm + i * 16 + fr) * BK + fg * 8];
        #pragma unroll
        for (int i = 0; i < 4; ++i) bfr[i] = *(const bf16x8*)&Bs[(wn + i * 16 + fr) * BK + fg * 8];
        #pragma unroll
        for (int i = 0; i < 4; ++i)
            #pragma unroll
            for (int j = 0; j < 4; ++j)
                acc[i][j] = __builtin_amdgcn_mfma_f32_16x16x32_bf16(af[i], bfr[j], acc[i][j], 0, 0, 0);
        __syncthreads();
    }

    #pragma unroll
    for (int i = 0; i < 4; ++i) {
        #pragma unroll
        for (int j = 0; j < 4; ++j) {
            int col = col0 + wn + j * 16 + fr;
            float bv = bias[col];
            #pragma unroll
            for (int r = 0; r < 4; ++r) {
                int row = row0 + wm + i * 16 + fg * 4 + r;
                Cf[(size_t)row * N + col] = acc[i][j][r] + bv;
            }
        }
    }
}

// ---------------- Flash attention v5 (r5 known-good, unchanged) ----------------
__global__ __launch_bounds__(512, 4) void attn_fwd5(const unsigned short* __restrict__ Qp,
                                                    const unsigned short* __restrict__ Kp,
                                                    const unsigned short* __restrict__ VTg,
                                                    unsigned short* __restrict__ ctx)
{
    __shared__ unsigned short Ks[64][68];
    __shared__ unsigned short Vt[64][68];
    __shared__ unsigned short Ps[8][16][68];

    const int lin = blockIdx.x;
    const int xcd = lin & 7;
    const int w = lin >> 3;
    const int bh = xcd * 8 + (w & 7);     // XCD owns 8 complete heads
    const int j = 15 - (w >> 3);          // heavy blocks first
    const int b = bh >> 4, h = bh & 15;
    const int tid = threadIdx.x, lane = tid & 63, wid = tid >> 6;
    const int fr = lane & 15, fg = lane >> 4;

    const unsigned short* Qh  = Qp  + (size_t)bh * (S_ * DH_);
    const unsigned short* Kh  = Kp  + (size_t)bh * (S_ * DH_);
    const unsigned short* VTh = VTg + (size_t)bh * (DH_ * S_);

    const int srow = tid >> 3;
    const int scol = (tid & 7) * 8;

    bf16x8 ones;
    #pragma unroll
    for (int i = 0; i < 8; ++i) ones[i] = (__bf16)1.0f;

    const int q0 = j * 128;
    const int ntiles = 2 * (j + 1);
    const int rbase = q0 + wid * 16;
    const int qg = rbase + fr;

    bf16x8 qf[2];
    #pragma unroll
    for (int ks = 0; ks < 2; ++ks)
        qf[ks] = *(const bf16x8*)&Qh[(size_t)qg * 64 + ks * 32 + 8 * fg];

    f32x4 oacc[4] = {};
    float m_run = -3.0e38f, l_run = 0.0f;

    int4 kreg = *(const int4*)&Kh[(size_t)srow * 64 + scol];
    int4 vreg = *(const int4*)&VTh[(size_t)srow * 2048 + scol];

    for (int kt = 0; kt < ntiles; ++kt) {
        const int kv0 = kt * 64;
        __syncthreads();
        *(int4*)&Ks[srow][scol] = kreg;
        *(int4*)&Vt[srow][scol] = vreg;
        if (kt + 1 < ntiles) {
            const int kv1 = kv0 + 64;
            kreg = *(const int4*)&Kh[(size_t)(kv1 + srow) * 64 + scol];
            vreg = *(const int4*)&VTh[(size_t)srow * 2048 + kv1 + scol];
        }
        __syncthreads();

        if (kv0 > rbase + 15) continue;

        f32x4 sacc[4] = {};
        #pragma unroll
        for (int nt = 0; nt < 4; ++nt)
            #pragma unroll
            for (int ks = 0; ks < 2; ++ks) {
                bf16x8 kf = *(const bf16x8*)&Ks[nt * 16 + fr][ks * 32 + 8 * fg];
                sacc[nt] = __builtin_amdgcn_mfma_f32_16x16x32_bf16(kf, qf[ks], sacc[nt], 0, 0, 0);
            }

        if (kv0 + 63 > rbase) {
            const int kbase = kv0 + fg * 4;
            #pragma unroll
            for (int nt = 0; nt < 4; ++nt)
                #pragma unroll
                for (int r = 0; r < 4; ++r)
                    if (kbase + nt * 16 + r > qg) sacc[nt][r] = -3.0e38f;
        }

        float vm = sacc[0][0];
        #pragma unroll
        for (int nt = 0; nt < 4; ++nt)
            #pragma unroll
            for (int r = 0; r < 4; ++r) vm = fmaxf(vm, sacc[nt][r]);
        vm = fmaxf(vm, __shfl_xor(vm, 16));
        vm = fmaxf(vm, __shfl_xor(vm, 32));

        if (!__all(vm - m_run <= 8.0f)) {
            const float mn = fmaxf(m_run, vm);
            const float alpha = exp2f(m_run - mn);
            m_run = mn;
            l_run *= alpha;
            #pragma unroll
            for (int dt = 0; dt < 4; ++dt)
                #pragma unroll
                for (int r = 0; r < 4; ++r) oacc[dt][r] *= alpha;
        }

        #pragma unroll
        for (int nt = 0; nt < 4; ++nt) {
            bf16x4 t;
            t[0] = (__bf16)exp2f(sacc[nt][0] - m_run);
            t[1] = (__bf16)exp2f(sacc[nt][1] - m_run);
            t[2] = (__bf16)exp2f(sacc[nt][2] - m_run);
            t[3] = (__bf16)exp2f(sacc[nt][3] - m_run);
            *(bf16x4*)&Ps[wid][fr][nt * 16 + fg * 4] = t;
        }
        asm volatile("s_waitcnt lgkmcnt(0)" ::: "memory");

        bf16x8 pb[2];
        #pragma unroll
        for (int ks = 0; ks < 2; ++ks)
            pb[ks] = *(const bf16x8*)&Ps[wid][fr][ks * 32 + 8 * fg];

        f32x4 racc = {};
        #pragma unroll
        for (int ks = 0; ks < 2; ++ks)
            racc = __builtin_amdgcn_mfma_f32_16x16x32_bf16(ones, pb[ks], racc, 0, 0, 0);
        #pragma unroll
        for (int dt = 0; dt < 4; ++dt)
            #pragma unroll
            for (int ks = 0; ks < 2; ++ks) {
                bf16x8 vf = *(const bf16x8*)&Vt[dt * 16 + fr][ks * 32 + 8 * fg];
                oacc[dt] = __builtin_amdgcn_mfma_f32_16x16x32_bf16(vf, pb[ks], oacc[dt], 0, 0, 0);
            }
        l_run += racc[0];
    }

    const float linv = 1.0f / l_run;
    unsigned short* cb = &ctx[(size_t)(b * 2048 + qg) * 1024 + h * 64];
    #pragma unroll
    for (int dt = 0; dt < 4; ++dt) {
        unsigned int w0 = f2bf(oacc[dt][0] * linv) | (f2bf(oacc[dt][1] * linv) << 16);
        unsigned int w1 = f2bf(oacc[dt][2] * linv) | (f2bf(oacc[dt][3] * linv) << 16);
        *(uint2*)&cb[dt * 16 + fg * 4] = make_uint2(w0, w1);
    }
}

extern "C" void kernel_launch(void* const* d_in, const int* in_sizes, int n_in,
                              void* d_out, int out_size, void* d_ws, size_t ws_size,
                              hipStream_t stream)
{
    const float* q  = (const float*)d_in[0];
    const float* k  = (const float*)d_in[1];
    const float* v  = (const float*)d_in[2];
    const float* Wq = (const float*)d_in[4];
    const float* bq = (const float*)d_in[5];
    const float* Wk = (const float*)d_in[6];
    const float* bk = (const float*)d_in[7];
    const float* Wv = (const float*)d_in[8];
    const float* bv = (const float*)d_in[9];
    const float* Wo = (const float*)d_in[10];
    const float* bo = (const float*)d_in[11];
    float* out = (float*)d_out;

    unsigned short* Wcat = (unsigned short*)d_ws;          // [Wq;Wk;Wv;Wo] bf16
    unsigned short* actb = Wcat + 4 * 1048576;             // [qb;kb;vb] bf16
    unsigned short* Qp   = actb + 3 * (size_t)NE_;
    unsigned short* Kp   = Qp + NE_;
    unsigned short* VTp  = Kp + NE_;                       // V in [B,H,DH,S]
    unsigned short* Ctx  = VTp + NE_;

    const float SCQ = 0.045084220027780106f;  // log2(e)/sqrt(D)

    dim3 blk(256);
    cvt_w4<<<dim3(1024, 4), blk, 0, stream>>>(Wq, Wk, Wv, Wo, Wcat);
    cvt_a3<<<dim3(8192, 3), blk, 0, stream>>>(q, k, v, actb);

    gemm_qkv8<<<dim3(384), dim3(512), 0, stream>>>(actb, Wcat, bq, bk, bv, Qp, Kp, VTp, SCQ);

    attn_fwd5<<<dim3(1024), dim3(512), 0, stream>>>(Qp, Kp, VTp, Ctx);

    gemm_o<<<dim3(64, 8), blk, 0, stream>>>(Ctx, Wcat + 3 * 1048576, bo, out);
}

// Round 9
// 201.341 us; speedup vs baseline: 1.0385x; 1.0203x over previous
//
#include <hip/hip_runtime.h>
#include <hip/hip_bf16.h>

#define S_ 2048
#define DH_ 64
#define NE_ 8388608  // 8192*1024 elems per activation tensor

using f32x4  = __attribute__((ext_vector_type(4))) float;
using bf16x8 = __attribute__((ext_vector_type(8))) __bf16;
using bf16x4 = __attribute__((ext_vector_type(4))) __bf16;

__device__ __forceinline__ unsigned int f2bf(float f) {
    union { float f; unsigned int u; } x; x.f = f;
    return (x.u + 0x7FFFu + ((x.u >> 16) & 1u)) >> 16;  // RNE
}

// async global->LDS, 16B per lane. LDS dest = wave-uniform base + lane*16.
__device__ __forceinline__ void gl_lds16(const unsigned short* g, unsigned short* l) {
    __builtin_amdgcn_global_load_lds(
        (const __attribute__((address_space(1))) unsigned int*)(const void*)g,
        (__attribute__((address_space(3))) unsigned int*)(void*)l,
        16, 0, 0);
}

// ---------------- weight cvt: 4 x [1024,1024] fp32 -> bf16, concat ----------------
__global__ __launch_bounds__(256) void cvt_w4(const float* __restrict__ w0, const float* __restrict__ w1,
                                              const float* __restrict__ w2, const float* __restrict__ w3,
                                              unsigned short* __restrict__ out) {
    const float* src = blockIdx.y == 0 ? w0 : blockIdx.y == 1 ? w1 : blockIdx.y == 2 ? w2 : w3;
    unsigned short* dst = out + (size_t)blockIdx.y * 1048576;
    int i = (blockIdx.x * 256 + threadIdx.x) * 4;
    float4 v = *(const float4*)&src[i];
    ushort4 h;
    h.x = f2bf(v.x); h.y = f2bf(v.y); h.z = f2bf(v.z); h.w = f2bf(v.w);
    *(ushort4*)&dst[i] = h;
}

// ---------------- activation cvt: q,k,v fp32 -> bf16, concat ----------------
__global__ __launch_bounds__(256) void cvt_a3(const float* __restrict__ a0, const float* __restrict__ a1,
                                              const float* __restrict__ a2, unsigned short* __restrict__ out) {
    const float* src = blockIdx.y == 0 ? a0 : blockIdx.y == 1 ? a1 : a2;
    unsigned short* dst = out + (size_t)blockIdx.y * NE_;
    int i = (blockIdx.x * 256 + threadIdx.x) * 4;
    float4 v = *(const float4*)&src[i];
    ushort4 h;
    h.x = f2bf(v.x); h.y = f2bf(v.y); h.z = f2bf(v.z); h.w = f2bf(v.w);
    *(ushort4*)&dst[i] = h;
}

// ---------------- fused QKV projection: 256^2 tile, 8-phase pipelined ----------------
// Slot-XOR swizzle (corrected r9): LDS slot t of row r holds global 8-elem slot
// t^(r&7) — written via pre-swizzled global source (linear gl_lds dest), read via
// slot (ks*4+fg)^(fr&7). Every 8-lane group covers 8 distinct 16B slots -> all 32
// banks, 2-way max (free). Counted vmcnt(4) at phases 4/8 only; never 0 in loop.
__global__ __launch_bounds__(512, 2) void gemm_qkv8(const unsigned short* __restrict__ actb,
                                                    const unsigned short* __restrict__ Wcat,
                                                    const float* __restrict__ bq,
                                                    const float* __restrict__ bk,
                                                    const float* __restrict__ bvv,
                                                    unsigned short* __restrict__ Qp,
                                                    unsigned short* __restrict__ Kp,
                                                    unsigned short* __restrict__ VTp,
                                                    float scq)
{
    __shared__ unsigned short lds[65536];   // elems: A [0,32768), B [32768,65536)
    unsigned short* ldsA = lds;
    unsigned short* ldsB = lds + 32768;

    // bijective XCD swizzle: nwg=384, q=48, r=0
    const int orig = blockIdx.x;
    const int lid = (orig & 7) * 48 + (orig >> 3);
    const int bx = lid & 31;        // 32 row tiles
    const int by = lid >> 5;        // 12 col tiles
    const int range = by >> 2;      // 0:Q 1:K 2:V
    const unsigned short* Aact = actb + (size_t)range * NE_;

    const int tid = threadIdx.x, lane = tid & 63, wid = tid >> 6;
    const int fr = lane & 15, fg = lane >> 4;
    const int wid_m = wid >> 2, wid_n = wid & 3;

    // staging maps (per-lane): lds linear dest, slot-XOR pre-swizzled global source
    const int srcRow0 = wid * 16 + (lane >> 3);                       // u=0; u=1: +8
    const int scolS = ((lane & 7) ^ ((lane >> 3) & 7)) << 3;          // elems

    auto STG = [&](int ldsRegion, const unsigned short* g, int grow, int kk) {
        const unsigned short* s0 = g + (size_t)(grow + srcRow0) * 1024 + kk + scolS;
        gl_lds16(s0, lds + ldsRegion + wid * 1024 + lane * 8);
        gl_lds16(s0 + 8 * 1024, lds + ldsRegion + wid * 1024 + 512 + lane * 8);
    };

    // ds_read bases (elems), slot-XOR swizzle: slot (ks*4+fg) ^ (fr&7)
    const int fx = fr & 7;
    const int vA0 = wid_m * 8192 + fr * 64 + ((fg ^ fx) << 3);
    const int vA1 = wid_m * 8192 + fr * 64 + (((4 | fg) ^ fx) << 3);
    const int vBr = (wid_n & 1) * 4096 + (wid_n >> 1) * 8192 + fr * 64;
    const int vB0 = vBr + ((fg ^ fx) << 3);
    const int vB1 = vBr + (((4 | fg) ^ fx) << 3);

    f32x4 acc[8][4] = {};
    bf16x8 bfr[4][2];

    // prologue: A-buf0<-T0 (h0,h1), B-buf0<-T0, B-buf1<-T1; retire first 8, keep 4
    STG(0,          Aact, bx * 256,       0);
    STG(8192,       Aact, bx * 256 + 128, 0);
    STG(32768,      Wcat, by * 256,       0);
    STG(32768+8192, Wcat, by * 256 + 128, 0);
    STG(32768+16384,       Wcat, by * 256,       64);
    STG(32768+16384+8192,  Wcat, by * 256 + 128,  64);
    asm volatile("s_waitcnt vmcnt(4)" ::: "memory");
    __builtin_amdgcn_s_barrier();

#define KTILE(BUF, ABUF, TA, BBUF, TB)                                              \
  {                                                                                 \
    _Pragma("unroll")                                                               \
    for (int q = 0; q < 4; ++q) {                                                   \
      if (q == 0) {                                                                 \
        _Pragma("unroll")                                                           \
        for (int j = 0; j < 4; ++j) {                                               \
          bfr[j][0] = *(const bf16x8*)&ldsB[(BUF)*16384 + vB0 + j*1024];            \
          bfr[j][1] = *(const bf16x8*)&ldsB[(BUF)*16384 + vB1 + j*1024];            \
        }                                                                           \
      }                                                                             \
      bf16x8 af[2][2];                                                              \
      _Pragma("unroll")                                                             \
      for (int i2 = 0; i2 < 2; ++i2) {                                              \
        af[i2][0] = *(const bf16x8*)&ldsA[(BUF)*16384 + vA0 + (q*2+i2)*1024];       \
        af[i2][1] = *(const bf16x8*)&ldsA[(BUF)*16384 + vA1 + (q*2+i2)*1024];       \
      }                                                                             \
      if (q == 0) STG((ABUF)*16384,        Aact, bx*256,       ((TA)&15)*64);       \
      if (q == 1) STG((ABUF)*16384 + 8192, Aact, bx*256 + 128, ((TA)&15)*64);       \
      if (q == 2) STG(32768 + (BBUF)*16384,        Wcat, by*256,       ((TB)&15)*64); \
      if (q == 3) { STG(32768 + (BBUF)*16384 + 8192, Wcat, by*256 + 128, ((TB)&15)*64); \
                    asm volatile("s_waitcnt vmcnt(4)" ::: "memory"); }              \
      __builtin_amdgcn_s_barrier();                                                 \
      asm volatile("s_waitcnt lgkmcnt(0)" ::: "memory");                            \
      __builtin_amdgcn_s_setprio(1);                                                \
      _Pragma("unroll")                                                             \
      for (int i2 = 0; i2 < 2; ++i2)                                                \
        _Pragma("unroll")                                                           \
        for (int j = 0; j < 4; ++j) {                                               \
          acc[q*2+i2][j] = __builtin_amdgcn_mfma_f32_16x16x32_bf16(af[i2][0], bfr[j][0], acc[q*2+i2][j], 0, 0, 0); \
          acc[q*2+i2][j] = __builtin_amdgcn_mfma_f32_16x16x32_bf16(af[i2][1], bfr[j][1], acc[q*2+i2][j], 0, 0, 0); \
        }                                                                           \
      __builtin_amdgcn_s_setprio(0);                                                \
      __builtin_amdgcn_s_barrier();                                                 \
    }                                                                               \
  }

    for (int it = 0; it < 8; ++it) {
        const int t0 = 2 * it;
        KTILE(0, 1, t0 + 1, 0, t0 + 2);   // phases 1-4: read buf0; stage A-buf1<-T1, B-buf0<-T2
        KTILE(1, 0, t0 + 2, 1, t0 + 3);   // phases 5-8: read buf1; stage A-buf0<-T2, B-buf1<-T3
    }
#undef KTILE

    asm volatile("s_waitcnt vmcnt(0)" ::: "memory");  // drain dummy prefetches before exit

    // epilogue: wave owns rows [wid_m*128,+128) x cols [wid_n*64,+64) of the 256^2 tile
    const float* bp = range == 0 ? bq : range == 1 ? bk : bvv;
    const float os = range == 0 ? scq : 1.0f;
    unsigned short* OP = range == 0 ? Qp : Kp;
    const int row00 = bx * 256 + wid_m * 128;
    const int col0r = (by & 3) * 256 + wid_n * 64;   // within range [0,1024)

    #pragma unroll
    for (int i = 0; i < 8; ++i) {
        #pragma unroll
        for (int j = 0; j < 4; ++j) {
            int colr = col0r + j * 16 + fr;
            float bias = bp[colr];
            int h = colr >> 6, dh = colr & 63;
            if (range == 2) {
                int row = row00 + i * 16 + fg * 4;
                int b = row >> 11, s = row & 2047;
                unsigned int w0 = f2bf(acc[i][j][0] + bias) | (f2bf(acc[i][j][1] + bias) << 16);
                unsigned int w1 = f2bf(acc[i][j][2] + bias) | (f2bf(acc[i][j][3] + bias) << 16);
                *(uint2*)&VTp[((size_t)((b << 4) + h) * 64 + dh) * 2048 + s] = make_uint2(w0, w1);
            } else {
                #pragma unroll
                for (int r = 0; r < 4; ++r) {
                    int row = row00 + i * 16 + fg * 4 + r;
                    int b = row >> 11, s = row & 2047;
                    OP[((((b << 4) + h) * 2048 + s) << 6) + dh] =
                        (unsigned short)f2bf((acc[i][j][r] + bias) * os);
                }
            }
        }
    }
}

// ---------------- output projection: fp32 out = Ctx @ Wo^T + bo (r5 known-good) ----------------
__global__ __launch_bounds__(256) void gemm_o(const unsigned short* __restrict__ A,
                                              const unsigned short* __restrict__ Bw,
                                              const float* __restrict__ bias,
                                              float* __restrict__ Cf)
{
    constexpr int K = 1024, BK = 32, N = 1024;
    __shared__ unsigned short As[128 * BK];
    __shared__ unsigned short Bs[128 * BK];

    const int tid = threadIdx.x, lane = tid & 63, wid = tid >> 6;
    const int row0 = blockIdx.x * 128, col0 = blockIdx.y * 128;
    const int wm = (wid >> 1) * 64, wn = (wid & 1) * 64;
    const int fr = lane & 15, fg = lane >> 4;

    f32x4 acc[4][4] = {};

    const int srow = wid * 16 + (lane >> 2);
    const int scol = (lane & 3) * 8;
    const size_t abase = (size_t)(row0 + srow) * K + scol;
    const size_t bbase = (size_t)(col0 + srow) * K + scol;
    unsigned short* lA0 = &As[srow * BK + scol];
    unsigned short* lA1 = &As[(srow + 64) * BK + scol];
    unsigned short* lB0 = &Bs[srow * BK + scol];
    unsigned short* lB1 = &Bs[(srow + 64) * BK + scol];

    for (int k0 = 0; k0 < K; k0 += BK) {
        gl_lds16(&A[abase + k0], lA0);
        gl_lds16(&A[abase + (size_t)64 * K + k0], lA1);
        gl_lds16(&Bw[bbase + k0], lB0);
        gl_lds16(&Bw[bbase + (size_t)64 * K + k0], lB1);
        __syncthreads();

        bf16x8 af[4], bfr[4];
        #pragma unroll
        for (int i = 0; i < 4; ++i) af[i] = *(const bf16x8*)&As[(wm + i * 16 + fr) * BK + fg * 8];
        #pragma unroll
        for (int i = 0; i < 4; ++i) bfr[i] = *(const bf16x8*)&Bs[(wn + i * 16 + fr) * BK + fg * 8];
        #pragma unroll
        for (int i = 0; i < 4; ++i)
            #pragma unroll
            for (int j = 0; j < 4; ++j)
                acc[i][j] = __builtin_amdgcn_mfma_f32_16x16x32_bf16(af[i], bfr[j], acc[i][j], 0, 0, 0);
        __syncthreads();
    }

    #pragma unroll
    for (int i = 0; i < 4; ++i) {
        #pragma unroll
        for (int j = 0; j < 4; ++j) {
            int col = col0 + wn + j * 16 + fr;
            float bv = bias[col];
            #pragma unroll
            for (int r = 0; r < 4; ++r) {
                int row = row0 + wm + i * 16 + fg * 4 + r;
                Cf[(size_t)row * N + col] = acc[i][j][r] + bv;
            }
        }
    }
}

// ---------------- Flash attention v5 (r5 known-good, unchanged) ----------------
__global__ __launch_bounds__(512, 4) void attn_fwd5(const unsigned short* __restrict__ Qp,
                                                    const unsigned short* __restrict__ Kp,
                                                    const unsigned short* __restrict__ VTg,
                                                    unsigned short* __restrict__ ctx)
{
    __shared__ unsigned short Ks[64][68];
    __shared__ unsigned short Vt[64][68];
    __shared__ unsigned short Ps[8][16][68];

    const int lin = blockIdx.x;
    const int xcd = lin & 7;
    const int w = lin >> 3;
    const int bh = xcd * 8 + (w & 7);     // XCD owns 8 complete heads
    const int j = 15 - (w >> 3);          // heavy blocks first
    const int b = bh >> 4, h = bh & 15;
    const int tid = threadIdx.x, lane = tid & 63, wid = tid >> 6;
    const int fr = lane & 15, fg = lane >> 4;

    const unsigned short* Qh  = Qp  + (size_t)bh * (S_ * DH_);
    const unsigned short* Kh  = Kp  + (size_t)bh * (S_ * DH_);
    const unsigned short* VTh = VTg + (size_t)bh * (DH_ * S_);

    const int srow = tid >> 3;
    const int scol = (tid & 7) * 8;

    bf16x8 ones;
    #pragma unroll
    for (int i = 0; i < 8; ++i) ones[i] = (__bf16)1.0f;

    const int q0 = j * 128;
    const int ntiles = 2 * (j + 1);
    const int rbase = q0 + wid * 16;
    const int qg = rbase + fr;

    bf16x8 qf[2];
    #pragma unroll
    for (int ks = 0; ks < 2; ++ks)
        qf[ks] = *(const bf16x8*)&Qh[(size_t)qg * 64 + ks * 32 + 8 * fg];

    f32x4 oacc[4] = {};
    float m_run = -3.0e38f, l_run = 0.0f;

    int4 kreg = *(const int4*)&Kh[(size_t)srow * 64 + scol];
    int4 vreg = *(const int4*)&VTh[(size_t)srow * 2048 + scol];

    for (int kt = 0; kt < ntiles; ++kt) {
        const int kv0 = kt * 64;
        __syncthreads();
        *(int4*)&Ks[srow][scol] = kreg;
        *(int4*)&Vt[srow][scol] = vreg;
        if (kt + 1 < ntiles) {
            const int kv1 = kv0 + 64;
            kreg = *(const int4*)&Kh[(size_t)(kv1 + srow) * 64 + scol];
            vreg = *(const int4*)&VTh[(size_t)srow * 2048 + kv1 + scol];
        }
        __syncthreads();

        if (kv0 > rbase + 15) continue;

        f32x4 sacc[4] = {};
        #pragma unroll
        for (int nt = 0; nt < 4; ++nt)
            #pragma unroll
            for (int ks = 0; ks < 2; ++ks) {
                bf16x8 kf = *(const bf16x8*)&Ks[nt * 16 + fr][ks * 32 + 8 * fg];
                sacc[nt] = __builtin_amdgcn_mfma_f32_16x16x32_bf16(kf, qf[ks], sacc[nt], 0, 0, 0);
            }

        if (kv0 + 63 > rbase) {
            const int kbase = kv0 + fg * 4;
            #pragma unroll
            for (int nt = 0; nt < 4; ++nt)
                #pragma unroll
                for (int r = 0; r < 4; ++r)
                    if (kbase + nt * 16 + r > qg) sacc[nt][r] = -3.0e38f;
        }

        float vm = sacc[0][0];
        #pragma unroll
        for (int nt = 0; nt < 4; ++nt)
            #pragma unroll
            for (int r = 0; r < 4; ++r) vm = fmaxf(vm, sacc[nt][r]);
        vm = fmaxf(vm, __shfl_xor(vm, 16));
        vm = fmaxf(vm, __shfl_xor(vm, 32));

        if (!__all(vm - m_run <= 8.0f)) {
            const float mn = fmaxf(m_run, vm);
            const float alpha = exp2f(m_run - mn);
            m_run = mn;
            l_run *= alpha;
            #pragma unroll
            for (int dt = 0; dt < 4; ++dt)
                #pragma unroll
                for (int r = 0; r < 4; ++r) oacc[dt][r] *= alpha;
        }

        #pragma unroll
        for (int nt = 0; nt < 4; ++nt) {
            bf16x4 t;
            t[0] = (__bf16)exp2f(sacc[nt][0] - m_run);
            t[1] = (__bf16)exp2f(sacc[nt][1] - m_run);
            t[2] = (__bf16)exp2f(sacc[nt][2] - m_run);
            t[3] = (__bf16)exp2f(sacc[nt][3] - m_run);
            *(bf16x4*)&Ps[wid][fr][nt * 16 + fg * 4] = t;
        }
        asm volatile("s_waitcnt lgkmcnt(0)" ::: "memory");

        bf16x8 pb[2];
        #pragma unroll
        for (int ks = 0; ks < 2; ++ks)
            pb[ks] = *(const bf16x8*)&Ps[wid][fr][ks * 32 + 8 * fg];

        f32x4 racc = {};
        #pragma unroll
        for (int ks = 0; ks < 2; ++ks)
            racc = __builtin_amdgcn_mfma_f32_16x16x32_bf16(ones, pb[ks], racc, 0, 0, 0);
        #pragma unroll
        for (int dt = 0; dt < 4; ++dt)
            #pragma unroll
            for (int ks = 0; ks < 2; ++ks) {
                bf16x8 vf = *(const bf16x8*)&Vt[dt * 16 + fr][ks * 32 + 8 * fg];
                oacc[dt] = __builtin_amdgcn_mfma_f32_16x16x32_bf16(vf, pb[ks], oacc[dt], 0, 0, 0);
            }
        l_run += racc[0];
    }

    const float linv = 1.0f / l_run;
    unsigned short* cb = &ctx[(size_t)(b * 2048 + qg) * 1024 + h * 64];
    #pragma unroll
    for (int dt = 0; dt < 4; ++dt) {
        unsigned int w0 = f2bf(oacc[dt][0] * linv) | (f2bf(oacc[dt][1] * linv) << 16);
        unsigned int w1 = f2bf(oacc[dt][2] * linv) | (f2bf(oacc[dt][3] * linv) << 16);
        *(uint2*)&cb[dt * 16 + fg * 4] = make_uint2(w0, w1);
    }
}

extern "C" void kernel_launch(void* const* d_in, const int* in_sizes, int n_in,
                              void* d_out, int out_size, void* d_ws, size_t ws_size,
                              hipStream_t stream)
{
    const float* q  = (const float*)d_in[0];
    const float* k  = (const float*)d_in[1];
    const float* v  = (const float*)d_in[2];
    const float* Wq = (const float*)d_in[4];
    const float* bq = (const float*)d_in[5];
    const float* Wk = (const float*)d_in[6];
    const float* bk = (const float*)d_in[7];
    const float* Wv = (const float*)d_in[8];
    const float* bv = (const float*)d_in[9];
    const float* Wo = (const float*)d_in[10];
    const float* bo = (const float*)d_in[11];
    float* out = (float*)d_out;

    unsigned short* Wcat = (unsigned short*)d_ws;          // [Wq;Wk;Wv;Wo] bf16
    unsigned short* actb = Wcat + 4 * 1048576;             // [qb;kb;vb] bf16
    unsigned short* Qp   = actb + 3 * (size_t)NE_;
    unsigned short* Kp   = Qp + NE_;
    unsigned short* VTp  = Kp + NE_;                       // V in [B,H,DH,S]
    unsigned short* Ctx  = VTp + NE_;

    const float SCQ = 0.045084220027780106f;  // log2(e)/sqrt(D)

    dim3 blk(256);
    cvt_w4<<<dim3(1024, 4), blk, 0, stream>>>(Wq, Wk, Wv, Wo, Wcat);
    cvt_a3<<<dim3(8192, 3), blk, 0, stream>>>(q, k, v, actb);

    gemm_qkv8<<<dim3(384), dim3(512), 0, stream>>>(actb, Wcat, bq, bk, bv, Qp, Kp, VTp, SCQ);

    attn_fwd5<<<dim3(1024), dim3(512), 0, stream>>>(Qp, Kp, VTp, Ctx);

    gemm_o<<<dim3(64, 8), blk, 0, stream>>>(Ctx, Wcat + 3 * 1048576, bo, out);
}